// Round 1
// baseline (3058.624 us; speedup 1.0000x reference)
//
#include <hip/hip_runtime.h>
#include <hip/hip_bf16.h>

// Problem constants (from reference)
constexpr int kNodes = 1000000;
constexpr int kEdges = 32000000;

// Packed accumulator format (u64 per node):
//   bits [48:63] : degree count (each edge endpoint adds 1)
//   bits [ 0:47] : fixed-point sum of neighbor orc values:
//                  each edge adds BIAS + round(orc * 2^20); bias keeps the
//                  field monotonically increasing (no borrow into deg field).
//   Decode: deg = p>>48 ; sum = ((p & 2^48-1) - deg*BIAS) / 2^20
//   Overflow bound: deg*(BIAS + 2^20) < 2^48  ->  deg <= 4095 (actual max ~130).
constexpr float kScale = 1048576.0f;          // 2^20
constexpr float kInvScale = 1.0f / 1048576.0f;
constexpr long long kBias = 1ll << 36;

__global__ __launch_bounds__(256) void zero_acc(unsigned long long* __restrict__ acc) {
    int i = blockIdx.x * 256 + threadIdx.x;
    if (i < kNodes) acc[i] = 0ull;
}

__global__ __launch_bounds__(256) void edge_kernel(
        const int* __restrict__ ei,
        const float* __restrict__ orc,
        unsigned long long* __restrict__ acc) {
    int t = blockIdx.x * 256 + threadIdx.x;
    int e0 = t * 4;
    if (e0 >= kEdges) return;
    // src row at [0, kEdges), dst row at [kEdges, 2*kEdges). kEdges % 4 == 0.
    const int4 s4 = *reinterpret_cast<const int4*>(ei + e0);
    const int4 d4 = *reinterpret_cast<const int4*>(ei + kEdges + e0);
    const int ss[4] = {s4.x, s4.y, s4.z, s4.w};
    const int dd[4] = {d4.x, d4.y, d4.z, d4.w};
    #pragma unroll
    for (int k = 0; k < 4; ++k) {
        const float os = orc[ss[k]];
        const float od = orc[dd[k]];
        // contribution of dst's orc to src node, and vice versa
        const unsigned long long ps =
            (1ull << 48) + (unsigned long long)(kBias + (long long)__float2ll_rn(od * kScale));
        const unsigned long long pd =
            (1ull << 48) + (unsigned long long)(kBias + (long long)__float2ll_rn(os * kScale));
        atomicAdd(&acc[ss[k]], ps);
        atomicAdd(&acc[dd[k]], pd);
    }
}

__global__ __launch_bounds__(256) void node_kernel(
        const float* __restrict__ orc,
        const unsigned long long* __restrict__ acc,
        const float* __restrict__ W1, const float* __restrict__ b1,
        const float* __restrict__ W2, const float* __restrict__ b2,
        const float* __restrict__ gamma, const float* __restrict__ beta,
        float* __restrict__ out) {
    const int i = blockIdx.x * 256 + threadIdx.x;
    if (i >= kNodes) return;

    const float x0 = orc[i];
    const unsigned long long p = acc[i];
    const unsigned deg = (unsigned)(p >> 48);
    const long long sf = (long long)(p & ((1ull << 48) - 1)) - (long long)deg * kBias;
    const float s = (float)sf * kInvScale;
    const float nb = (deg > 0) ? s / (float)deg : 0.0f;

    // Harmonic encoding: norm = clip((x+1)/(2+1e-8),0,1); interleaved sin/cos of k*pi*norm, k=1..4
    constexpr float kPi = 3.14159265358979323846f;
    float Phi[16];
    const float n0 = __saturatef((x0 + 1.0f) * 0.5f);   // (2+1e-8) rounds to 2.0f in fp32
    const float n1 = __saturatef((nb + 1.0f) * 0.5f);
    #pragma unroll
    for (int k = 0; k < 4; ++k) {
        const float a0 = n0 * (float)(k + 1) * kPi;
        const float a1 = n1 * (float)(k + 1) * kPi;
        Phi[2 * k]     = __sinf(a0);
        Phi[2 * k + 1] = __cosf(a0);
        Phi[8 + 2 * k]     = __sinf(a1);
        Phi[8 + 2 * k + 1] = __cosf(a1);
    }

    // MLP: h = relu(W1 @ Phi + b1) [32], y = W2 @ h + b2 [16]
    // Weight indices are wave-uniform -> compiler emits scalar (s_load) reads.
    float y[16];
    #pragma unroll
    for (int d = 0; d < 16; ++d) y[d] = b2[d];
    #pragma unroll
    for (int j = 0; j < 32; ++j) {
        float a = b1[j];
        #pragma unroll
        for (int d = 0; d < 16; ++d) a = fmaf(Phi[d], W1[j * 16 + d], a);
        a = fmaxf(a, 0.0f);
        #pragma unroll
        for (int d = 0; d < 16; ++d) y[d] = fmaf(a, W2[d * 32 + j], y[d]);
    }

    // LayerNorm over 16 dims + affine + residual(Phi)
    float mu = 0.0f;
    #pragma unroll
    for (int d = 0; d < 16; ++d) mu += y[d];
    mu *= (1.0f / 16.0f);
    float var = 0.0f;
    #pragma unroll
    for (int d = 0; d < 16; ++d) { const float t = y[d] - mu; var = fmaf(t, t, var); }
    var *= (1.0f / 16.0f);
    const float inv = rsqrtf(var + 1e-5f);

    float4* o4 = reinterpret_cast<float4*>(out + (size_t)i * 16);
    #pragma unroll
    for (int q = 0; q < 4; ++q) {
        float4 o;
        o.x = (y[4 * q + 0] - mu) * inv * gamma[4 * q + 0] + beta[4 * q + 0] + Phi[4 * q + 0];
        o.y = (y[4 * q + 1] - mu) * inv * gamma[4 * q + 1] + beta[4 * q + 1] + Phi[4 * q + 1];
        o.z = (y[4 * q + 2] - mu) * inv * gamma[4 * q + 2] + beta[4 * q + 2] + Phi[4 * q + 2];
        o.w = (y[4 * q + 3] - mu) * inv * gamma[4 * q + 3] + beta[4 * q + 3] + Phi[4 * q + 3];
        o4[q] = o;
    }
}

extern "C" void kernel_launch(void* const* d_in, const int* in_sizes, int n_in,
                              void* d_out, int out_size, void* d_ws, size_t ws_size,
                              hipStream_t stream) {
    const float* orc   = (const float*)d_in[0];
    const int*   ei    = (const int*)d_in[1];
    const float* W1    = (const float*)d_in[2];
    const float* b1    = (const float*)d_in[3];
    const float* W2    = (const float*)d_in[4];
    const float* b2    = (const float*)d_in[5];
    const float* gamma = (const float*)d_in[6];
    const float* beta  = (const float*)d_in[7];
    float* out = (float*)d_out;
    unsigned long long* acc = (unsigned long long*)d_ws;  // 8 MB

    zero_acc<<<(kNodes + 255) / 256, 256, 0, stream>>>(acc);
    edge_kernel<<<(kEdges / 4 + 255) / 256, 256, 0, stream>>>(ei, orc, acc);
    node_kernel<<<(kNodes + 255) / 256, 256, 0, stream>>>(
        orc, acc, W1, b1, W2, b2, gamma, beta, out);
}

// Round 2
// 2491.148 us; speedup vs baseline: 1.2278x; 1.2278x over previous
//
#include <hip/hip_runtime.h>
#include <hip/hip_bf16.h>

constexpr int kNodes = 1000000;
constexpr int kEdges = 32000000;

// ---------------- Partitioned-scatter path ----------------
// 2048 buckets x 512 nodes. Record: u32 = (node&511)<<22 | fix21(orc_other),
// fix21(x) = round((x+1)*2^21) clamped to 2^22-1 (error <= 2^-22).
// Accumulator (per node, u64): deg<<42 | sum(fix21) ; sum < deg*2^22, deg<2^20.
constexpr int NB = 2048;
constexpr int BSHIFT = 9;
constexpr int BNODES = 512;
constexpr int NBUSED = ((kNodes - 1) >> BSHIFT) + 1;   // 1954
constexpr int CAP = 36352;     // per-bucket record capacity: mean 32768 + 19.8 sigma
constexpr int SBLK = 2048;     // scatter blocks
constexpr int EPB = kEdges / SBLK;  // 15625 edges per block (exact)

constexpr size_t kRecBytes = (size_t)NB * CAP * 4;           // ~298 MB
constexpr size_t kCurOff  = kRecBytes;                        // NB u32
constexpr size_t kAccOff  = kRecBytes + (size_t)NB * 4;       // kNodes u64 (8B aligned)
constexpr size_t kWsNeeded = kAccOff + (size_t)kNodes * 8;

__global__ __launch_bounds__(256) void zero_cursor(unsigned* __restrict__ cur) {
    int i = blockIdx.x * 256 + threadIdx.x;
    if (i < NB) cur[i] = 0u;
}

__global__ __launch_bounds__(256) void scatter_kernel(
        const int* __restrict__ ei, const float* __restrict__ orc,
        unsigned* __restrict__ rec, unsigned* __restrict__ cursor) {
    __shared__ unsigned hist[NB];                 // 8 KB: counts -> bases -> cursors
    const int tid = threadIdx.x;
    const int e0 = blockIdx.x * EPB, e1 = e0 + EPB;

    for (int k = tid; k < NB; k += 256) hist[k] = 0u;
    __syncthreads();

    // pass A: per-block bucket histogram
    for (int e = e0 + tid; e < e1; e += 256) {
        const int s = ei[e];
        const int d = ei[kEdges + e];
        atomicAdd(&hist[s >> BSHIFT], 1u);
        atomicAdd(&hist[d >> BSHIFT], 1u);
    }
    __syncthreads();

    // reserve contiguous global range per bucket (one returning atomic each)
    for (int k = tid; k < NB; k += 256) {
        const unsigned c = hist[k];
        hist[k] = c ? atomicAdd(&cursor[k], c) : 0u;
    }
    __syncthreads();

    // pass B: rank via LDS cursor, write record
    for (int e = e0 + tid; e < e1; e += 256) {
        const int s = ei[e];
        const int d = ei[kEdges + e];
        const float os = orc[s];
        const float od = orc[d];
        unsigned qs = __float2uint_rn((od + 1.0f) * 2097152.0f);  // value landing at s
        unsigned qd = __float2uint_rn((os + 1.0f) * 2097152.0f);  // value landing at d
        qs = qs > 4194303u ? 4194303u : qs;
        qd = qd > 4194303u ? 4194303u : qd;
        const int bs = s >> BSHIFT, bd = d >> BSHIFT;
        const unsigned rs = atomicAdd(&hist[bs], 1u);
        const unsigned rd = atomicAdd(&hist[bd], 1u);
        if (rs < (unsigned)CAP)
            rec[(size_t)bs * CAP + rs] = ((unsigned)(s & (BNODES - 1)) << 22) | qs;
        if (rd < (unsigned)CAP)
            rec[(size_t)bd * CAP + rd] = ((unsigned)(d & (BNODES - 1)) << 22) | qd;
    }
}

__global__ __launch_bounds__(256) void bucket_accum(
        const unsigned* __restrict__ rec, const unsigned* __restrict__ cursor,
        unsigned long long* __restrict__ acc) {
    __shared__ unsigned long long lacc[BNODES];   // 4 KB
    const int b = blockIdx.x;
    const int tid = threadIdx.x;
    lacc[tid] = 0ull;
    lacc[tid + 256] = 0ull;
    __syncthreads();
    unsigned cnt = cursor[b];
    if (cnt > (unsigned)CAP) cnt = (unsigned)CAP;
    const unsigned* __restrict__ r = rec + (size_t)b * CAP;
    for (unsigned i = tid; i < cnt; i += 256) {
        const unsigned v = r[i];
        atomicAdd(&lacc[v >> 22], (1ull << 42) | (unsigned long long)(v & 0x3FFFFFu));
    }
    __syncthreads();
    const int n0 = (b << BSHIFT) + tid;
    if (n0 < kNodes) acc[n0] = lacc[tid];
    const int n1 = n0 + 256;
    if (n1 < kNodes) acc[n1] = lacc[tid + 256];
}

// ---------------- Fallback (atomic) path ----------------
constexpr float kScale = 1048576.0f;           // 2^20
constexpr float kInvScale = 1.0f / 1048576.0f;
constexpr long long kBias = 1ll << 36;

__global__ __launch_bounds__(256) void zero_acc(unsigned long long* __restrict__ acc) {
    int i = blockIdx.x * 256 + threadIdx.x;
    if (i < kNodes) acc[i] = 0ull;
}

__global__ __launch_bounds__(256) void edge_kernel(
        const int* __restrict__ ei,
        const float* __restrict__ orc,
        unsigned long long* __restrict__ acc) {
    int t = blockIdx.x * 256 + threadIdx.x;
    int e0 = t * 4;
    if (e0 >= kEdges) return;
    const int4 s4 = *reinterpret_cast<const int4*>(ei + e0);
    const int4 d4 = *reinterpret_cast<const int4*>(ei + kEdges + e0);
    const int ss[4] = {s4.x, s4.y, s4.z, s4.w};
    const int dd[4] = {d4.x, d4.y, d4.z, d4.w};
    #pragma unroll
    for (int k = 0; k < 4; ++k) {
        const float os = orc[ss[k]];
        const float od = orc[dd[k]];
        const unsigned long long ps =
            (1ull << 48) + (unsigned long long)(kBias + (long long)__float2ll_rn(od * kScale));
        const unsigned long long pd =
            (1ull << 48) + (unsigned long long)(kBias + (long long)__float2ll_rn(os * kScale));
        atomicAdd(&acc[ss[k]], ps);
        atomicAdd(&acc[dd[k]], pd);
    }
}

// ---------------- Node phase ----------------
// MODE 0: old packing (deg<<48 | biased 2^20 fixed sum)
// MODE 1: new packing (deg<<42 | sum of fix21), nb = sum*2^-21/deg - 1
template <int MODE>
__global__ __launch_bounds__(256) void node_kernel(
        const float* __restrict__ orc,
        const unsigned long long* __restrict__ acc,
        const float* __restrict__ W1, const float* __restrict__ b1,
        const float* __restrict__ W2, const float* __restrict__ b2,
        const float* __restrict__ gamma, const float* __restrict__ beta,
        float* __restrict__ out) {
    const int i = blockIdx.x * 256 + threadIdx.x;
    if (i >= kNodes) return;

    const float x0 = orc[i];
    const unsigned long long p = acc[i];
    float nb;
    if (MODE == 0) {
        const unsigned deg = (unsigned)(p >> 48);
        const long long sf = (long long)(p & ((1ull << 48) - 1)) - (long long)deg * kBias;
        const float s = (float)sf * kInvScale;
        nb = (deg > 0) ? s / (float)deg : 0.0f;
    } else {
        const unsigned deg = (unsigned)(p >> 42);
        const unsigned long long sumv = p & ((1ull << 42) - 1);
        nb = (deg > 0) ? ((float)sumv * (1.0f / 2097152.0f) / (float)deg - 1.0f) : 0.0f;
    }

    constexpr float kPi = 3.14159265358979323846f;
    float Phi[16];
    const float n0 = __saturatef((x0 + 1.0f) * 0.5f);
    const float n1 = __saturatef((nb + 1.0f) * 0.5f);
    #pragma unroll
    for (int k = 0; k < 4; ++k) {
        const float a0 = n0 * (float)(k + 1) * kPi;
        const float a1 = n1 * (float)(k + 1) * kPi;
        Phi[2 * k]     = __sinf(a0);
        Phi[2 * k + 1] = __cosf(a0);
        Phi[8 + 2 * k]     = __sinf(a1);
        Phi[8 + 2 * k + 1] = __cosf(a1);
    }

    float y[16];
    #pragma unroll
    for (int d = 0; d < 16; ++d) y[d] = b2[d];
    #pragma unroll
    for (int j = 0; j < 32; ++j) {
        float a = b1[j];
        #pragma unroll
        for (int d = 0; d < 16; ++d) a = fmaf(Phi[d], W1[j * 16 + d], a);
        a = fmaxf(a, 0.0f);
        #pragma unroll
        for (int d = 0; d < 16; ++d) y[d] = fmaf(a, W2[d * 32 + j], y[d]);
    }

    float mu = 0.0f;
    #pragma unroll
    for (int d = 0; d < 16; ++d) mu += y[d];
    mu *= (1.0f / 16.0f);
    float var = 0.0f;
    #pragma unroll
    for (int d = 0; d < 16; ++d) { const float t = y[d] - mu; var = fmaf(t, t, var); }
    var *= (1.0f / 16.0f);
    const float inv = rsqrtf(var + 1e-5f);

    float4* o4 = reinterpret_cast<float4*>(out + (size_t)i * 16);
    #pragma unroll
    for (int q = 0; q < 4; ++q) {
        float4 o;
        o.x = (y[4 * q + 0] - mu) * inv * gamma[4 * q + 0] + beta[4 * q + 0] + Phi[4 * q + 0];
        o.y = (y[4 * q + 1] - mu) * inv * gamma[4 * q + 1] + beta[4 * q + 1] + Phi[4 * q + 1];
        o.z = (y[4 * q + 2] - mu) * inv * gamma[4 * q + 2] + beta[4 * q + 2] + Phi[4 * q + 2];
        o.w = (y[4 * q + 3] - mu) * inv * gamma[4 * q + 3] + beta[4 * q + 3] + Phi[4 * q + 3];
        o4[q] = o;
    }
}

extern "C" void kernel_launch(void* const* d_in, const int* in_sizes, int n_in,
                              void* d_out, int out_size, void* d_ws, size_t ws_size,
                              hipStream_t stream) {
    const float* orc   = (const float*)d_in[0];
    const int*   ei    = (const int*)d_in[1];
    const float* W1    = (const float*)d_in[2];
    const float* b1    = (const float*)d_in[3];
    const float* W2    = (const float*)d_in[4];
    const float* b2    = (const float*)d_in[5];
    const float* gamma = (const float*)d_in[6];
    const float* beta  = (const float*)d_in[7];
    float* out = (float*)d_out;
    char* ws = (char*)d_ws;

    if (ws_size >= kWsNeeded) {
        unsigned* rec = (unsigned*)ws;
        unsigned* cursor = (unsigned*)(ws + kCurOff);
        unsigned long long* acc = (unsigned long long*)(ws + kAccOff);
        zero_cursor<<<(NB + 255) / 256, 256, 0, stream>>>(cursor);
        scatter_kernel<<<SBLK, 256, 0, stream>>>(ei, orc, rec, cursor);
        bucket_accum<<<NBUSED, 256, 0, stream>>>(rec, cursor, acc);
        node_kernel<1><<<(kNodes + 255) / 256, 256, 0, stream>>>(
            orc, acc, W1, b1, W2, b2, gamma, beta, out);
    } else {
        unsigned long long* acc = (unsigned long long*)ws;  // 8 MB
        zero_acc<<<(kNodes + 255) / 256, 256, 0, stream>>>(acc);
        edge_kernel<<<(kEdges / 4 + 255) / 256, 256, 0, stream>>>(ei, orc, acc);
        node_kernel<0><<<(kNodes + 255) / 256, 256, 0, stream>>>(
            orc, acc, W1, b1, W2, b2, gamma, beta, out);
    }
}

// Round 3
// 863.335 us; speedup vs baseline: 3.5428x; 2.8855x over previous
//
#include <hip/hip_runtime.h>
#include <hip/hip_bf16.h>

constexpr int kNodes = 1000000;
constexpr int kEdges = 32000000;

// ---------------- Tile-sorted scatter path ----------------
// 256 buckets x 4096 nodes. Record u32 = (node&4095)<<20 | q20,
// q20 = clamp(round((orc_other+1)*2^19), 0, 0xFFFFF)  (error <= 2^-20).
// Edges processed in tiles of 4096 (=> 8192 records). Within a tile, records
// are counting-sorted by bucket into a reorder buffer whose per-bucket counts
// are padded to a multiple of 4 records (16 B) so every segment is int4-
// aligned; pad slots hold sentinel 0xFFFFFFFF. The whole tile is flushed to
// rec[tile*TSTRIDE ...] with coalesced full-line int4 stores. Per-(bucket,
// tile) start offsets stored u16 in [bucket][tile] layout (rows 0..256;
// row 256 = padded total of tile).
constexpr int NB = 256;
constexpr int BSHIFT = 12;
constexpr int BNODES = 4096;
constexpr int NBUSED = (kNodes + BNODES - 1) / BNODES;   // 245
constexpr int EPT = 4096;                 // edges per tile
constexpr int TILES = (kEdges + EPT - 1) / EPT;          // 7813
constexpr int TSTRIDE = 8960;             // 2*EPT + 256*3 padding, mult of 4

constexpr size_t kRecBytes = (size_t)TILES * TSTRIDE * 4;        // ~280 MB
constexpr size_t kTblOff   = kRecBytes;
constexpr size_t kTblBytes = ((size_t)(NB + 1) * TILES * 2 + 15) & ~(size_t)15;
constexpr size_t kAccOff   = kTblOff + kTblBytes;
constexpr size_t kWsNeeded = kAccOff + (size_t)kNodes * 8;

__global__ __launch_bounds__(512) void scatter_sort(
        const int* __restrict__ ei, const float* __restrict__ orc,
        unsigned* __restrict__ rec, unsigned short* __restrict__ tbl) {
    __shared__ alignas(16) int es[EPT];          // 16 KB
    __shared__ alignas(16) int ed[EPT];          // 16 KB
    __shared__ alignas(16) unsigned reorder[TSTRIDE];  // 35 KB
    __shared__ unsigned cnt[NB];                 // hist -> cursor
    __shared__ unsigned scanbuf[NB];             // inclusive scan of padded cnt
    const int tid = threadIdx.x;
    const int t = blockIdx.x;
    const int e0 = t * EPT;
    const int ne = min(EPT, kEdges - e0);        // 4096, last tile 2048 (mult of 4)

    for (int k = tid; k < NB; k += 512) cnt[k] = 0u;
    for (int k = tid; k < TSTRIDE; k += 512) reorder[k] = 0xFFFFFFFFu;
    __syncthreads();

    // phase 1: coalesced edge load -> LDS stage + bucket histogram
    for (int k4 = tid * 4; k4 < ne; k4 += 2048) {
        const int4 s4 = *reinterpret_cast<const int4*>(ei + e0 + k4);
        const int4 d4 = *reinterpret_cast<const int4*>(ei + kEdges + e0 + k4);
        *reinterpret_cast<int4*>(es + k4) = s4;
        *reinterpret_cast<int4*>(ed + k4) = d4;
        atomicAdd(&cnt[s4.x >> BSHIFT], 1u);
        atomicAdd(&cnt[s4.y >> BSHIFT], 1u);
        atomicAdd(&cnt[s4.z >> BSHIFT], 1u);
        atomicAdd(&cnt[s4.w >> BSHIFT], 1u);
        atomicAdd(&cnt[d4.x >> BSHIFT], 1u);
        atomicAdd(&cnt[d4.y >> BSHIFT], 1u);
        atomicAdd(&cnt[d4.z >> BSHIFT], 1u);
        atomicAdd(&cnt[d4.w >> BSHIFT], 1u);
    }
    __syncthreads();

    // phase 2: Hillis-Steele inclusive scan of padded counts
    if (tid < NB) scanbuf[tid] = (cnt[tid] + 3u) & ~3u;
    __syncthreads();
    for (int off = 1; off < NB; off <<= 1) {
        unsigned v = 0u;
        if (tid < NB && tid >= off) v = scanbuf[tid - off];
        __syncthreads();
        if (tid < NB) scanbuf[tid] += v;
        __syncthreads();
    }
    if (tid < NB) {
        const unsigned pc = (cnt[tid] + 3u) & ~3u;
        const unsigned st = scanbuf[tid] - pc;
        tbl[(size_t)tid * TILES + t] = (unsigned short)st;
        cnt[tid] = st;                            // becomes rank cursor
    }
    if (tid == 0) tbl[(size_t)NB * TILES + t] = (unsigned short)scanbuf[NB - 1];
    __syncthreads();

    // phase 3: rank + build records into reorder buffer
    for (int k4 = tid * 4; k4 < ne; k4 += 2048) {
        #pragma unroll
        for (int j = 0; j < 4; ++j) {
            const int k = k4 + j;
            const int s = es[k], d = ed[k];
            const float os = orc[s], od = orc[d];
            unsigned qs = __float2uint_rn((od + 1.0f) * 524288.0f);
            unsigned qd = __float2uint_rn((os + 1.0f) * 524288.0f);
            qs = qs > 0xFFFFFu ? 0xFFFFFu : qs;
            qd = qd > 0xFFFFFu ? 0xFFFFFu : qd;
            const unsigned rs = atomicAdd(&cnt[s >> BSHIFT], 1u);
            reorder[rs] = ((unsigned)(s & (BNODES - 1)) << 20) | qs;
            const unsigned rd = atomicAdd(&cnt[d >> BSHIFT], 1u);
            reorder[rd] = ((unsigned)(d & (BNODES - 1)) << 20) | qd;
        }
    }
    __syncthreads();

    // phase 4: coalesced full-line flush of the sorted tile
    const unsigned total = scanbuf[NB - 1];       // padded total, mult of 4
    unsigned* __restrict__ g = rec + (size_t)t * TSTRIDE;
    for (unsigned k = tid * 4; k < total; k += 2048)
        *reinterpret_cast<int4*>(g + k) = *reinterpret_cast<const int4*>(reorder + k);
}

__global__ __launch_bounds__(512) void bucket_accum(
        const unsigned* __restrict__ rec, const unsigned short* __restrict__ tbl,
        unsigned long long* __restrict__ acc) {
    __shared__ unsigned long long lacc[BNODES];   // 32 KB
    const int b = blockIdx.x;
    const int tid = threadIdx.x;
    for (int k = tid; k < BNODES; k += 512) lacc[k] = 0ull;
    __syncthreads();
    const unsigned short* __restrict__ r0 = tbl + (size_t)b * TILES;
    const unsigned short* __restrict__ r1 = tbl + (size_t)(b + 1) * TILES;
    for (int t = tid; t < TILES; t += 512) {
        const unsigned st = r0[t];
        const unsigned en = r1[t];
        const uint4* __restrict__ p =
            reinterpret_cast<const uint4*>(rec + (size_t)t * TSTRIDE + st);
        const unsigned n4 = (en - st) >> 2;
        for (unsigned i = 0; i < n4; ++i) {
            const uint4 v = p[i];
            const unsigned long long a0 = (v.x == 0xFFFFFFFFu) ? 0ull
                : ((1ull << 42) | (unsigned long long)(v.x & 0xFFFFFu));
            atomicAdd(&lacc[v.x >> 20], a0);
            const unsigned long long a1 = (v.y == 0xFFFFFFFFu) ? 0ull
                : ((1ull << 42) | (unsigned long long)(v.y & 0xFFFFFu));
            atomicAdd(&lacc[v.y >> 20], a1);
            const unsigned long long a2 = (v.z == 0xFFFFFFFFu) ? 0ull
                : ((1ull << 42) | (unsigned long long)(v.z & 0xFFFFFu));
            atomicAdd(&lacc[v.z >> 20], a2);
            const unsigned long long a3 = (v.w == 0xFFFFFFFFu) ? 0ull
                : ((1ull << 42) | (unsigned long long)(v.w & 0xFFFFFu));
            atomicAdd(&lacc[v.w >> 20], a3);
        }
    }
    __syncthreads();
    const int base = b << BSHIFT;
    for (int k = tid; k < BNODES; k += 512) {
        const int n = base + k;
        if (n < kNodes) acc[n] = lacc[k];
    }
}

// ---------------- Fallback (atomic) path ----------------
constexpr float kScale = 1048576.0f;           // 2^20
constexpr float kInvScale = 1.0f / 1048576.0f;
constexpr long long kBias = 1ll << 36;

__global__ __launch_bounds__(256) void zero_acc(unsigned long long* __restrict__ acc) {
    int i = blockIdx.x * 256 + threadIdx.x;
    if (i < kNodes) acc[i] = 0ull;
}

__global__ __launch_bounds__(256) void edge_kernel(
        const int* __restrict__ ei,
        const float* __restrict__ orc,
        unsigned long long* __restrict__ acc) {
    int t = blockIdx.x * 256 + threadIdx.x;
    int e0 = t * 4;
    if (e0 >= kEdges) return;
    const int4 s4 = *reinterpret_cast<const int4*>(ei + e0);
    const int4 d4 = *reinterpret_cast<const int4*>(ei + kEdges + e0);
    const int ss[4] = {s4.x, s4.y, s4.z, s4.w};
    const int dd[4] = {d4.x, d4.y, d4.z, d4.w};
    #pragma unroll
    for (int k = 0; k < 4; ++k) {
        const float os = orc[ss[k]];
        const float od = orc[dd[k]];
        const unsigned long long ps =
            (1ull << 48) + (unsigned long long)(kBias + (long long)__float2ll_rn(od * kScale));
        const unsigned long long pd =
            (1ull << 48) + (unsigned long long)(kBias + (long long)__float2ll_rn(os * kScale));
        atomicAdd(&acc[ss[k]], ps);
        atomicAdd(&acc[dd[k]], pd);
    }
}

// ---------------- Node phase ----------------
// MODE 0: deg<<48 | biased 2^20 fixed sum.  MODE 2: deg<<42 | sum(q20).
template <int MODE>
__global__ __launch_bounds__(256) void node_kernel(
        const float* __restrict__ orc,
        const unsigned long long* __restrict__ acc,
        const float* __restrict__ W1, const float* __restrict__ b1,
        const float* __restrict__ W2, const float* __restrict__ b2,
        const float* __restrict__ gamma, const float* __restrict__ beta,
        float* __restrict__ out) {
    const int i = blockIdx.x * 256 + threadIdx.x;
    if (i >= kNodes) return;

    const float x0 = orc[i];
    const unsigned long long p = acc[i];
    float nb;
    if (MODE == 0) {
        const unsigned deg = (unsigned)(p >> 48);
        const long long sf = (long long)(p & ((1ull << 48) - 1)) - (long long)deg * kBias;
        const float s = (float)sf * kInvScale;
        nb = (deg > 0) ? s / (float)deg : 0.0f;
    } else {
        const unsigned deg = (unsigned)(p >> 42);
        const unsigned long long sumq = p & ((1ull << 42) - 1);
        nb = (deg > 0) ? ((float)sumq * (1.0f / 524288.0f) / (float)deg - 1.0f) : 0.0f;
    }

    constexpr float kPi = 3.14159265358979323846f;
    float Phi[16];
    const float n0 = __saturatef((x0 + 1.0f) * 0.5f);
    const float n1 = __saturatef((nb + 1.0f) * 0.5f);
    #pragma unroll
    for (int k = 0; k < 4; ++k) {
        const float a0 = n0 * (float)(k + 1) * kPi;
        const float a1 = n1 * (float)(k + 1) * kPi;
        Phi[2 * k]     = __sinf(a0);
        Phi[2 * k + 1] = __cosf(a0);
        Phi[8 + 2 * k]     = __sinf(a1);
        Phi[8 + 2 * k + 1] = __cosf(a1);
    }

    float y[16];
    #pragma unroll
    for (int d = 0; d < 16; ++d) y[d] = b2[d];
    #pragma unroll
    for (int j = 0; j < 32; ++j) {
        float a = b1[j];
        #pragma unroll
        for (int d = 0; d < 16; ++d) a = fmaf(Phi[d], W1[j * 16 + d], a);
        a = fmaxf(a, 0.0f);
        #pragma unroll
        for (int d = 0; d < 16; ++d) y[d] = fmaf(a, W2[d * 32 + j], y[d]);
    }

    float mu = 0.0f;
    #pragma unroll
    for (int d = 0; d < 16; ++d) mu += y[d];
    mu *= (1.0f / 16.0f);
    float var = 0.0f;
    #pragma unroll
    for (int d = 0; d < 16; ++d) { const float t = y[d] - mu; var = fmaf(t, t, var); }
    var *= (1.0f / 16.0f);
    const float inv = rsqrtf(var + 1e-5f);

    float4* o4 = reinterpret_cast<float4*>(out + (size_t)i * 16);
    #pragma unroll
    for (int q = 0; q < 4; ++q) {
        float4 o;
        o.x = (y[4 * q + 0] - mu) * inv * gamma[4 * q + 0] + beta[4 * q + 0] + Phi[4 * q + 0];
        o.y = (y[4 * q + 1] - mu) * inv * gamma[4 * q + 1] + beta[4 * q + 1] + Phi[4 * q + 1];
        o.z = (y[4 * q + 2] - mu) * inv * gamma[4 * q + 2] + beta[4 * q + 2] + Phi[4 * q + 2];
        o.w = (y[4 * q + 3] - mu) * inv * gamma[4 * q + 3] + beta[4 * q + 3] + Phi[4 * q + 3];
        o4[q] = o;
    }
}

extern "C" void kernel_launch(void* const* d_in, const int* in_sizes, int n_in,
                              void* d_out, int out_size, void* d_ws, size_t ws_size,
                              hipStream_t stream) {
    const float* orc   = (const float*)d_in[0];
    const int*   ei    = (const int*)d_in[1];
    const float* W1    = (const float*)d_in[2];
    const float* b1    = (const float*)d_in[3];
    const float* W2    = (const float*)d_in[4];
    const float* b2    = (const float*)d_in[5];
    const float* gamma = (const float*)d_in[6];
    const float* beta  = (const float*)d_in[7];
    float* out = (float*)d_out;
    char* ws = (char*)d_ws;

    if (ws_size >= kWsNeeded) {
        unsigned* rec = (unsigned*)ws;
        unsigned short* tbl = (unsigned short*)(ws + kTblOff);
        unsigned long long* acc = (unsigned long long*)(ws + kAccOff);
        scatter_sort<<<TILES, 512, 0, stream>>>(ei, orc, rec, tbl);
        bucket_accum<<<NBUSED, 512, 0, stream>>>(rec, tbl, acc);
        node_kernel<2><<<(kNodes + 255) / 256, 256, 0, stream>>>(
            orc, acc, W1, b1, W2, b2, gamma, beta, out);
    } else {
        unsigned long long* acc = (unsigned long long*)ws;  // 8 MB
        zero_acc<<<(kNodes + 255) / 256, 256, 0, stream>>>(acc);
        edge_kernel<<<(kEdges / 4 + 255) / 256, 256, 0, stream>>>(ei, orc, acc);
        node_kernel<0><<<(kNodes + 255) / 256, 256, 0, stream>>>(
            orc, acc, W1, b1, W2, b2, gamma, beta, out);
    }
}